// Round 2
// baseline (6455.698 us; speedup 1.0000x reference)
//
#include <hip/hip_runtime.h>
#include <math.h>

#define B_ 256
#define T_ 64
#define DOBS 512
#define D_ 128
#define N_ 16
#define H_ 256

__device__ __forceinline__ float sigmoidf_(float x) {
    return 1.0f / (1.0f + expf(-x));
}

// LN stats for 16 slot rows; threads 0..15, lane-rotated reads to dodge bank conflicts
__device__ __forceinline__ void slot_ln_stats(const float* slots_s, float* mu_s,
                                              float* rs_s, int tid) {
    if (tid < 16) {
        const float* row = slots_s + tid * 128;
        float s = 0.0f;
        for (int j = 0; j < 128; ++j) { int c = (j + 2 * tid) & 127; s += row[c]; }
        float mu = s * (1.0f / 128.0f);
        float v = 0.0f;
        for (int j = 0; j < 128; ++j) {
            int c = (j + 2 * tid) & 127;
            float d = row[c] - mu;
            v = fmaf(d, d, v);
        }
        mu_s[tid] = mu;
        rs_s[tid] = rsqrtf(v * (1.0f / 128.0f) + 1e-5f);
    }
}

__global__ __launch_bounds__(256) void sa_kernel(
    const float* __restrict__ obs,
    const float* __restrict__ eW1, const float* __restrict__ eb1,
    const float* __restrict__ eW2, const float* __restrict__ eb2,
    const float* __restrict__ skipW, const float* __restrict__ slot_mu,
    const float* __restrict__ Wk, const float* __restrict__ Wv, const float* __restrict__ Wq,
    const float* __restrict__ Wih, const float* __restrict__ Whh,
    const float* __restrict__ bih, const float* __restrict__ bhh,
    const float* __restrict__ mW1, const float* __restrict__ mb1,
    const float* __restrict__ mW2, const float* __restrict__ mb2,
    const float* __restrict__ g_in, const float* __restrict__ be_in,
    const float* __restrict__ g_sl, const float* __restrict__ be_sl,
    const float* __restrict__ g_ml, const float* __restrict__ be_ml,
    float* __restrict__ out)
{
    __shared__ float obs_s[DOBS];
    __shared__ float h_s[H_];
    __shared__ float z_s[D_];
    __shared__ float inp_s[D_];
    __shared__ float k_s[D_];
    __shared__ float v_s[D_];
    __shared__ float slots_s[N_ * D_];
    __shared__ float ln_s[N_ * D_];
    __shared__ float q_s[N_ * D_];   // also reused: GRU newh, MLP hidden
    __shared__ float attn_s[N_];
    __shared__ float mu_s[N_], rs_s[N_];
    __shared__ float zstat[2];

    const int tid = threadIdx.x;
    const int r = blockIdx.x;              // r = b*T + t
    const float* op = obs + (size_t)r * DOBS;

    for (int i = tid; i < DOBS; i += 256) obs_s[i] = op[i];
    __syncthreads();

    // ---- encoder layer 1: h = gelu(obs@W1 + b1), exact gelu ----
    {
        float acc = eb1[tid];
        for (int k = 0; k < DOBS; ++k)
            acc = fmaf(obs_s[k], eW1[k * H_ + tid], acc);
        h_s[tid] = 0.5f * acc * (1.0f + erff(acc * 0.7071067811865475f));
    }
    __syncthreads();

    // ---- z = tanh(h@W2 + b2 + obs@skip) ----
    if (tid < D_) {
        float acc = eb2[tid];
        for (int k = 0; k < H_; ++k)
            acc = fmaf(h_s[k], eW2[k * D_ + tid], acc);
        for (int k = 0; k < DOBS; ++k)
            acc = fmaf(obs_s[k], skipW[k * D_ + tid], acc);
        z_s[tid] = tanhf(acc);
    }
    __syncthreads();

    // ---- LN(z) ----
    if (tid == 0) {
        float s = 0.0f;
        for (int j = 0; j < D_; ++j) s += z_s[j];
        float mu = s * (1.0f / 128.0f);
        float v = 0.0f;
        for (int j = 0; j < D_; ++j) { float d = z_s[j] - mu; v = fmaf(d, d, v); }
        zstat[0] = mu;
        zstat[1] = rsqrtf(v * (1.0f / 128.0f) + 1e-5f);
    }
    // init slots while thread0 works
    for (int i = tid; i < N_ * D_; i += 256) slots_s[i] = slot_mu[i];
    __syncthreads();
    if (tid < D_)
        inp_s[tid] = (z_s[tid] - zstat[0]) * zstat[1] * g_in[tid] + be_in[tid];
    __syncthreads();

    // ---- k = inp@Wk, v = inp@Wv ----
    {
        int col = tid & 127, sel = tid >> 7;
        const float* W = sel ? Wv : Wk;
        float acc = 0.0f;
        for (int k = 0; k < D_; ++k)
            acc = fmaf(inp_s[k], W[k * D_ + col], acc);
        (sel ? v_s : k_s)[col] = acc;
    }
    __syncthreads();

    const int col = tid & 127;
    const int half = tid >> 7;

    for (int iter = 0; iter < 3; ++iter) {
        // ---- q = LN(slots) @ Wq ----
        slot_ln_stats(slots_s, mu_s, rs_s, tid);
        __syncthreads();
        for (int i = tid; i < N_ * D_; i += 256) {
            int n = i >> 7, d = i & 127;
            ln_s[i] = (slots_s[i] - mu_s[n]) * rs_s[n] * g_sl[d] + be_sl[d];
        }
        __syncthreads();
        {
            float acc[8] = {0, 0, 0, 0, 0, 0, 0, 0};
            for (int k = 0; k < D_; ++k) {
                float w = Wq[k * D_ + col];
#pragma unroll
                for (int i = 0; i < 8; ++i)
                    acc[i] = fmaf(ln_s[(half * 8 + i) * D_ + k], w, acc[i]);
            }
#pragma unroll
            for (int i = 0; i < 8; ++i) q_s[(half * 8 + i) * D_ + col] = acc[i];
        }
        __syncthreads();

        // ---- logits = q.k / sqrt(D); softmax over slots ----
        if (tid < N_) {
            float lg = 0.0f;
            for (int j = 0; j < D_; ++j) {
                int c = (j + 2 * tid) & 127;
                lg = fmaf(q_s[tid * D_ + c], k_s[c], lg);
            }
            attn_s[tid] = lg * 0.08838834764831845f;  // 1/sqrt(128)
        }
        __syncthreads();
        if (tid == 0) {
            float mx = attn_s[0];
            for (int n = 1; n < N_; ++n) mx = fmaxf(mx, attn_s[n]);
            float e[N_], s = 0.0f;
            for (int n = 0; n < N_; ++n) { e[n] = expf(attn_s[n] - mx); s += e[n]; }
            float inv = 1.0f / s;
            for (int n = 0; n < N_; ++n) attn_s[n] = e[n] * inv;
        }
        __syncthreads();

        // ---- GRU: x = attn[n]*v, h = slots ----
        {
            float a[8];
#pragma unroll
            for (int i = 0; i < 8; ++i) a[i] = attn_s[half * 8 + i];
            float gir[8] = {0}, giz[8] = {0}, gin_[8] = {0};
            float ghr[8] = {0}, ghz[8] = {0}, ghn[8] = {0};
            for (int k = 0; k < D_; ++k) {
                float vk = v_s[k];
                float wr = Wih[k * 384 + col];
                float wz = Wih[k * 384 + 128 + col];
                float wn = Wih[k * 384 + 256 + col];
                float hr = Whh[k * 384 + col];
                float hz = Whh[k * 384 + 128 + col];
                float hn = Whh[k * 384 + 256 + col];
#pragma unroll
                for (int i = 0; i < 8; ++i) {
                    float u = a[i] * vk;
                    float sl = slots_s[(half * 8 + i) * D_ + k];
                    gir[i] = fmaf(u, wr, gir[i]);
                    giz[i] = fmaf(u, wz, giz[i]);
                    gin_[i] = fmaf(u, wn, gin_[i]);
                    ghr[i] = fmaf(sl, hr, ghr[i]);
                    ghz[i] = fmaf(sl, hz, ghz[i]);
                    ghn[i] = fmaf(sl, hn, ghn[i]);
                }
            }
            float bir = bih[col], biz = bih[128 + col], bin_ = bih[256 + col];
            float bhr = bhh[col], bhz = bhh[128 + col], bhn = bhh[256 + col];
#pragma unroll
            for (int i = 0; i < 8; ++i) {
                int n = half * 8 + i;
                float rg = sigmoidf_((gir[i] + bir) + (ghr[i] + bhr));
                float zg = sigmoidf_((giz[i] + biz) + (ghz[i] + bhz));
                float ng = tanhf((gin_[i] + bin_) + rg * (ghn[i] + bhn));
                float hprev = slots_s[n * D_ + col];
                q_s[n * D_ + col] = (1.0f - zg) * ng + zg * hprev;  // newh staged
            }
        }
        __syncthreads();
        for (int i = tid; i < N_ * D_; i += 256) slots_s[i] = q_s[i];
        __syncthreads();

        // ---- MLP residual: slots += relu(LN(slots)@W1+b1)@W2+b2 ----
        slot_ln_stats(slots_s, mu_s, rs_s, tid);
        __syncthreads();
        for (int i = tid; i < N_ * D_; i += 256) {
            int n = i >> 7, d = i & 127;
            ln_s[i] = (slots_s[i] - mu_s[n]) * rs_s[n] * g_ml[d] + be_ml[d];
        }
        __syncthreads();
        {
            float acc[8] = {0, 0, 0, 0, 0, 0, 0, 0};
            for (int k = 0; k < D_; ++k) {
                float w = mW1[k * D_ + col];
#pragma unroll
                for (int i = 0; i < 8; ++i)
                    acc[i] = fmaf(ln_s[(half * 8 + i) * D_ + k], w, acc[i]);
            }
            float bb = mb1[col];
#pragma unroll
            for (int i = 0; i < 8; ++i)
                q_s[(half * 8 + i) * D_ + col] = fmaxf(acc[i] + bb, 0.0f);
        }
        __syncthreads();
        {
            float acc[8] = {0, 0, 0, 0, 0, 0, 0, 0};
            for (int k = 0; k < D_; ++k) {
                float w = mW2[k * D_ + col];
#pragma unroll
                for (int i = 0; i < 8; ++i)
                    acc[i] = fmaf(q_s[(half * 8 + i) * D_ + k], w, acc[i]);
            }
            float bb = mb2[col];
#pragma unroll
            for (int i = 0; i < 8; ++i)
                slots_s[(half * 8 + i) * D_ + col] += acc[i] + bb;
        }
        __syncthreads();
    }

    // ---- F.normalize + store ----
    if (tid < N_) {
        float s = 0.0f;
        for (int j = 0; j < D_; ++j) {
            int c = (j + 2 * tid) & 127;
            float x = slots_s[tid * D_ + c];
            s = fmaf(x, x, s);
        }
        rs_s[tid] = 1.0f / fmaxf(sqrtf(s), 1e-8f);
    }
    __syncthreads();
    size_t base = (size_t)r * (N_ * D_);
    for (int i = tid; i < N_ * D_; i += 256) {
        int n = i >> 7;
        out[base + i] = slots_s[i] * rs_s[n];
    }
}

// temporal blend step t (in-place on out): out[:,t] = 0.7*out[:,t] + 0.3*tanh(out[:,t-1]@Wt)
__global__ __launch_bounds__(256) void temporal_kernel(
    const float* __restrict__ Wt, float* __restrict__ out, int t)
{
    __shared__ float prev_s[2][D_];
    const int tid = threadIdx.x;
    const int col = tid & 127, half = tid >> 7;
    const int row = blockIdx.x * 2 + half;  // 0..B*N-1
    const int b = row >> 4, n = row & 15;
    const size_t prevOff = (((size_t)b * T_ + (t - 1)) * N_ + n) * D_;
    const size_t curOff = (((size_t)b * T_ + t) * N_ + n) * D_;
    prev_s[half][col] = out[prevOff + col];
    __syncthreads();
    float acc = 0.0f;
    for (int k = 0; k < D_; ++k)
        acc = fmaf(prev_s[half][k], Wt[k * D_ + col], acc);
    float sa = out[curOff + col];
    out[curOff + col] = 0.7f * sa + 0.3f * tanhf(acc);
}

extern "C" void kernel_launch(void* const* d_in, const int* in_sizes, int n_in,
                              void* d_out, int out_size, void* d_ws, size_t ws_size,
                              hipStream_t stream) {
    const float* obs   = (const float*)d_in[0];
    const float* eW1   = (const float*)d_in[1];
    const float* eb1   = (const float*)d_in[2];
    const float* eW2   = (const float*)d_in[3];
    const float* eb2   = (const float*)d_in[4];
    const float* skipW = (const float*)d_in[5];
    const float* smu   = (const float*)d_in[6];
    const float* Wk    = (const float*)d_in[7];
    const float* Wv    = (const float*)d_in[8];
    const float* Wq    = (const float*)d_in[9];
    const float* Wih   = (const float*)d_in[10];
    const float* Whh   = (const float*)d_in[11];
    const float* bih   = (const float*)d_in[12];
    const float* bhh   = (const float*)d_in[13];
    const float* mW1   = (const float*)d_in[14];
    const float* mb1   = (const float*)d_in[15];
    const float* mW2   = (const float*)d_in[16];
    const float* mb2   = (const float*)d_in[17];
    const float* g_in  = (const float*)d_in[18];
    const float* be_in = (const float*)d_in[19];
    const float* g_sl  = (const float*)d_in[20];
    const float* be_sl = (const float*)d_in[21];
    const float* g_ml  = (const float*)d_in[22];
    const float* be_ml = (const float*)d_in[23];
    const float* Wt    = (const float*)d_in[24];
    float* out = (float*)d_out;

    sa_kernel<<<B_ * T_, 256, 0, stream>>>(
        obs, eW1, eb1, eW2, eb2, skipW, smu, Wk, Wv, Wq, Wih, Whh, bih, bhh,
        mW1, mb1, mW2, mb2, g_in, be_in, g_sl, be_sl, g_ml, be_ml, out);

    for (int t = 1; t < T_; ++t)
        temporal_kernel<<<(B_ * N_) / 2, 256, 0, stream>>>(Wt, out, t);
}

// Round 3
// 3184.430 us; speedup vs baseline: 2.0273x; 2.0273x over previous
//
#include <hip/hip_runtime.h>
#include <math.h>

#define B_ 256
#define T_ 64
#define DOBS 512
#define D_ 128
#define N_ 16
#define H_ 256

typedef unsigned short u16;
typedef short bf16x8 __attribute__((ext_vector_type(8)));
typedef float f32x4 __attribute__((ext_vector_type(4)));

union FragU { bf16x8 v; uint4 u; };

#define MFMA(ACC, A, Bv) (ACC) = __builtin_amdgcn_mfma_f32_16x16x32_bf16((A), (Bv), (ACC), 0, 0, 0)
#define MFMA2(ACC, AH, AL, Bv) do { MFMA(ACC, AH, Bv); MFMA(ACC, AL, Bv); } while (0)

// ws layout (u16 elements), all matrices transposed to [n][k] bf16:
#define OFF_EW1T   0        // 256x512
#define OFF_EW2T   131072   // 128x256
#define OFF_SKIPT  163840   // 128x512
#define OFF_WKVT   229376   // 256x128 (rows 0-127 Wk, 128-255 Wv)
#define OFF_WQT    262144   // 128x128
#define OFF_WIHT   278528   // 384x128
#define OFF_WHHT   327680   // 384x128
#define OFF_MW1T   376832   // 128x128
#define OFF_MW2T   393216   // 128x128
#define OFF_WTT    409600   // 128x128

__device__ __forceinline__ unsigned rne16(float f) {
    unsigned u = __float_as_uint(f);
    return (u + 0x7FFFu + ((u >> 16) & 1u)) >> 16;
}
__device__ __forceinline__ float fromhi(unsigned h) { return __uint_as_float(h << 16); }
__device__ __forceinline__ u16 f2b(float f) { return (u16)rne16(f); }
__device__ __forceinline__ float sigmoidf_(float x) { return 1.0f / (1.0f + expf(-x)); }

__device__ __forceinline__ void mk_pack(const float* x, FragU& fh, FragU& fl) {
    unsigned h[8], l[8];
#pragma unroll
    for (int j = 0; j < 8; ++j) {
        h[j] = rne16(x[j]);
        l[j] = rne16(x[j] - fromhi(h[j]));
    }
    fh.u = make_uint4(h[0] | (h[1] << 16), h[2] | (h[3] << 16), h[4] | (h[5] << 16), h[6] | (h[7] << 16));
    fl.u = make_uint4(l[0] | (l[1] << 16), l[2] | (l[3] << 16), l[4] | (l[5] << 16), l[6] | (l[7] << 16));
}

__device__ __forceinline__ void mk_raw(const float* p, FragU& fh, FragU& fl) {
    float4 a = *(const float4*)p, b = *(const float4*)(p + 4);
    float x[8] = {a.x, a.y, a.z, a.w, b.x, b.y, b.z, b.w};
    mk_pack(x, fh, fl);
}

__device__ __forceinline__ void mk_aff(const float* p, float mu, float rs,
                                       const float* gp, const float* bp,
                                       FragU& fh, FragU& fl) {
    float4 a = *(const float4*)p, b = *(const float4*)(p + 4);
    float4 g0 = *(const float4*)gp, g1 = *(const float4*)(gp + 4);
    float4 b0 = *(const float4*)bp, b1 = *(const float4*)(bp + 4);
    float x[8];
    x[0] = (a.x - mu) * rs * g0.x + b0.x;  x[1] = (a.y - mu) * rs * g0.y + b0.y;
    x[2] = (a.z - mu) * rs * g0.z + b0.z;  x[3] = (a.w - mu) * rs * g0.w + b0.w;
    x[4] = (b.x - mu) * rs * g1.x + b1.x;  x[5] = (b.y - mu) * rs * g1.y + b1.y;
    x[6] = (b.z - mu) * rs * g1.z + b1.z;  x[7] = (b.w - mu) * rs * g1.w + b1.w;
    mk_pack(x, fh, fl);
}

__device__ __forceinline__ void mk_scaled(const float* p, float sc, FragU& fh, FragU& fl) {
    float4 a = *(const float4*)p, b = *(const float4*)(p + 4);
    float x[8] = {sc * a.x, sc * a.y, sc * a.z, sc * a.w, sc * b.x, sc * b.y, sc * b.z, sc * b.w};
    mk_pack(x, fh, fl);
}

// ---------------- weight prepass: fp32 [k][n] -> bf16 [n][k] ----------------
__global__ __launch_bounds__(256) void prep_kernel(
    const float* __restrict__ eW1, const float* __restrict__ eW2, const float* __restrict__ skipW,
    const float* __restrict__ Wk, const float* __restrict__ Wv, const float* __restrict__ Wq,
    const float* __restrict__ Wih, const float* __restrict__ Whh,
    const float* __restrict__ mW1, const float* __restrict__ mW2, const float* __restrict__ Wt,
    u16* __restrict__ ws)
{
    int id = blockIdx.y;
    const float* src; int dstoff, logk, N;
    switch (id) {
        case 0:  src = eW1;   dstoff = OFF_EW1T;  logk = 9; N = 256; break;
        case 1:  src = eW2;   dstoff = OFF_EW2T;  logk = 8; N = 128; break;
        case 2:  src = skipW; dstoff = OFF_SKIPT; logk = 9; N = 128; break;
        case 3:  src = Wk;    dstoff = OFF_WKVT;  logk = 7; N = 128; break;
        case 4:  src = Wv;    dstoff = OFF_WKVT + 16384; logk = 7; N = 128; break;
        case 5:  src = Wq;    dstoff = OFF_WQT;   logk = 7; N = 128; break;
        case 6:  src = Wih;   dstoff = OFF_WIHT;  logk = 7; N = 384; break;
        case 7:  src = Whh;   dstoff = OFF_WHHT;  logk = 7; N = 384; break;
        case 8:  src = mW1;   dstoff = OFF_MW1T;  logk = 7; N = 128; break;
        case 9:  src = mW2;   dstoff = OFF_MW2T;  logk = 7; N = 128; break;
        default: src = Wt;    dstoff = OFF_WTT;   logk = 7; N = 128; break;
    }
    int idx = blockIdx.x * 256 + threadIdx.x;
    int K = 1 << logk;
    if (idx < K * N) {
        int n = idx >> logk, k = idx & (K - 1);
        ws[dstoff + idx] = f2b(src[k * N + n]);
    }
}

// ---------------- main fused kernel: 4 (b,t) rows per block ----------------
__global__ __launch_bounds__(256) void sa2_kernel(
    const float* __restrict__ obs,
    const float* __restrict__ eb1, const float* __restrict__ eb2,
    const float* __restrict__ slot_mu,
    const float* __restrict__ bih, const float* __restrict__ bhh,
    const float* __restrict__ mb1, const float* __restrict__ mb2,
    const float* __restrict__ g_in, const float* __restrict__ be_in,
    const float* __restrict__ g_sl, const float* __restrict__ be_sl,
    const float* __restrict__ g_ml, const float* __restrict__ be_ml,
    const u16* __restrict__ ws, float* __restrict__ out)
{
    __shared__ __align__(16) float slots_s[64 * 132];      // 33792 B
    __shared__ __align__(16) float scratch[4352];          // enc: obs(4x516)+h(4x260)+z(4x132); iter: hid u16 4x16x136
    __shared__ __align__(16) float k_s[4 * 132];
    __shared__ __align__(16) float v_s[4 * 132];
    __shared__ __align__(16) float par_s[6 * 128];         // gin, bin, gsl, bsl, gml, bml
    __shared__ __align__(16) float bias_s[512];            // b_rz[256], bin_[128], bhn_[128]
    __shared__ float rs_s[64];
    __shared__ float logit_s[64];
    __shared__ float zmu_s[4], zrs_s[4];

    float* obs_s = scratch;            // 4 x 516
    float* h_s   = scratch + 2064;     // 4 x 260
    float* z_s   = scratch + 3104;     // 4 x 132
    u16*   hid_s = (u16*)scratch;      // 4 groups x 16 x 136 (iter phase)

    const int tid = threadIdx.x;
    const int wave = tid >> 6, lane = tid & 63;
    const int l15 = lane & 15, quad = lane >> 4;
    const int r0 = blockIdx.x * 4;

    // ---- stage params / biases / obs ----
    if (tid < 128) {
        par_s[tid]       = g_in[tid];  par_s[128 + tid] = be_in[tid];
        par_s[256 + tid] = g_sl[tid];  par_s[384 + tid] = be_sl[tid];
        par_s[512 + tid] = g_ml[tid];  par_s[640 + tid] = be_ml[tid];
        bias_s[256 + tid] = bih[256 + tid];
        bias_s[384 + tid] = bhh[256 + tid];
    }
    if (tid < 256) bias_s[tid] = bih[tid] + bhh[tid];
    for (int i = tid; i < 2048; i += 256) {
        int g = i >> 9, c = i & 511;
        obs_s[g * 516 + c] = obs[(size_t)(r0 + g) * 512 + c];
    }
    __syncthreads();

    // ---- encoder layer 1: h = gelu(obs@W1 + b1); M-tile has rows 0-3 valid ----
    {
        f32x4 acc[4] = {{0}, {0}, {0}, {0}};
        const float* abase = obs_s + (l15 & 3) * 516;
        for (int ks = 0; ks < 16; ++ks) {
            FragU ah, al;
            mk_raw(abase + ks * 32 + quad * 8, ah, al);
#pragma unroll
            for (int tt = 0; tt < 4; ++tt) {
                int row = (wave * 4 + tt) * 16 + l15;
                FragU b; b.u = *(const uint4*)(ws + OFF_EW1T + row * 512 + ks * 32 + quad * 8);
                MFMA2(acc[tt], ah.v, al.v, b.v);
            }
        }
        if (quad == 0) {
#pragma unroll
            for (int tt = 0; tt < 4; ++tt) {
                int col = (wave * 4 + tt) * 16 + l15;
                float bb = eb1[col];
#pragma unroll
                for (int reg = 0; reg < 4; ++reg) {
                    float x = acc[tt][reg] + bb;
                    h_s[reg * 260 + col] = 0.5f * x * (1.0f + erff(x * 0.7071067811865475f));
                }
            }
        }
    }
    __syncthreads();

    // ---- z = tanh(h@W2 + b2 + obs@skip) ----
    {
        f32x4 acc[2] = {{0}, {0}};
        const float* hbase = h_s + (l15 & 3) * 260;
        for (int ks = 0; ks < 8; ++ks) {
            FragU ah, al;
            mk_raw(hbase + ks * 32 + quad * 8, ah, al);
#pragma unroll
            for (int tt = 0; tt < 2; ++tt) {
                int row = (wave * 2 + tt) * 16 + l15;
                FragU b; b.u = *(const uint4*)(ws + OFF_EW2T + row * 256 + ks * 32 + quad * 8);
                MFMA2(acc[tt], ah.v, al.v, b.v);
            }
        }
        const float* obase = obs_s + (l15 & 3) * 516;
        for (int ks = 0; ks < 16; ++ks) {
            FragU ah, al;
            mk_raw(obase + ks * 32 + quad * 8, ah, al);
#pragma unroll
            for (int tt = 0; tt < 2; ++tt) {
                int row = (wave * 2 + tt) * 16 + l15;
                FragU b; b.u = *(const uint4*)(ws + OFF_SKIPT + row * 512 + ks * 32 + quad * 8);
                MFMA2(acc[tt], ah.v, al.v, b.v);
            }
        }
        if (quad == 0) {
#pragma unroll
            for (int tt = 0; tt < 2; ++tt) {
                int col = (wave * 2 + tt) * 16 + l15;
                float bb = eb2[col];
#pragma unroll
                for (int reg = 0; reg < 4; ++reg)
                    z_s[reg * 132 + col] = tanhf(acc[tt][reg] + bb);
            }
        }
    }
    __syncthreads();

    // ---- LN(z) stats (4 rows) ----
    if (tid < 4) {
        const float* row = z_s + tid * 132;
        float s = 0.0f;
        for (int j = 0; j < 128; ++j) s += row[j];
        float mu = s * (1.0f / 128.0f), v = 0.0f;
        for (int j = 0; j < 128; ++j) { float d = row[j] - mu; v = fmaf(d, d, v); }
        zmu_s[tid] = mu;
        zrs_s[tid] = rsqrtf(v * (1.0f / 128.0f) + 1e-5f);
    }
    __syncthreads();

    // ---- k,v = LN(z) @ [Wk|Wv] ----
    {
        f32x4 acc[4] = {{0}, {0}, {0}, {0}};
        const float* zbase = z_s + (l15 & 3) * 132;
        float zmu = zmu_s[l15 & 3], zrs = zrs_s[l15 & 3];
        for (int ks = 0; ks < 4; ++ks) {
            FragU ah, al;
            mk_aff(zbase + ks * 32 + quad * 8, zmu, zrs,
                   par_s + ks * 32 + quad * 8, par_s + 128 + ks * 32 + quad * 8, ah, al);
#pragma unroll
            for (int tt = 0; tt < 4; ++tt) {
                int row = (wave * 4 + tt) * 16 + l15;
                FragU b; b.u = *(const uint4*)(ws + OFF_WKVT + row * 128 + ks * 32 + quad * 8);
                MFMA2(acc[tt], ah.v, al.v, b.v);
            }
        }
        if (quad == 0) {
#pragma unroll
            for (int tt = 0; tt < 4; ++tt) {
                int col = (wave * 4 + tt) * 16 + l15;
#pragma unroll
                for (int reg = 0; reg < 4; ++reg) {
                    if (col < 128) k_s[reg * 132 + col] = acc[tt][reg];
                    else           v_s[reg * 132 + col - 128] = acc[tt][reg];
                }
            }
        }
    }
    __syncthreads();

    // ---- slot loop: wave w owns group g=w ----
    const int g = wave;
    const int srow0 = g * 16;
    for (int i = lane; i < 2048; i += 64)
        slots_s[(srow0 + (i >> 7)) * 132 + (i & 127)] = slot_mu[i];
    __syncthreads();

    for (int iter = 0; iter < 3; ++iter) {
        // LN stats of own row (l15); strided-4 reads (2-way free)
        float myMu, myRs;
        {
            const float* rowp = slots_s + (srow0 + l15) * 132;
            float s = 0.0f;
            for (int j = 0; j < 32; ++j) s += rowp[quad + 4 * j];
            s += __shfl_xor(s, 16); s += __shfl_xor(s, 32);
            myMu = s * (1.0f / 128.0f);
            float v = 0.0f;
            for (int j = 0; j < 32; ++j) { float d = rowp[quad + 4 * j] - myMu; v = fmaf(d, d, v); }
            v += __shfl_xor(v, 16); v += __shfl_xor(v, 32);
            myRs = rsqrtf(v * (1.0f / 128.0f) + 1e-5f);
        }

        // ---- q = LN(slots)@Wq fused with logits ----
        {
            FragU ah[4], al[4];
#pragma unroll
            for (int ks = 0; ks < 4; ++ks)
                mk_aff(slots_s + (srow0 + l15) * 132 + ks * 32 + quad * 8, myMu, myRs,
                       par_s + 256 + ks * 32 + quad * 8, par_s + 384 + ks * 32 + quad * 8,
                       ah[ks], al[ks]);
            float lp[4] = {0, 0, 0, 0};
            for (int t = 0; t < 8; ++t) {
                f32x4 a = {0};
#pragma unroll
                for (int ks = 0; ks < 4; ++ks) {
                    FragU b; b.u = *(const uint4*)(ws + OFF_WQT + (t * 16 + l15) * 128 + ks * 32 + quad * 8);
                    MFMA2(a, ah[ks].v, al[ks].v, b.v);
                }
                float kc = k_s[g * 132 + t * 16 + l15];
#pragma unroll
                for (int reg = 0; reg < 4; ++reg) lp[reg] = fmaf(a[reg], kc, lp[reg]);
            }
#pragma unroll
            for (int reg = 0; reg < 4; ++reg) {
                lp[reg] += __shfl_xor(lp[reg], 1);
                lp[reg] += __shfl_xor(lp[reg], 2);
                lp[reg] += __shfl_xor(lp[reg], 4);
                lp[reg] += __shfl_xor(lp[reg], 8);
            }
            if (l15 == 0) {
#pragma unroll
                for (int reg = 0; reg < 4; ++reg)
                    logit_s[srow0 + quad * 4 + reg] = lp[reg] * 0.08838834764831845f;
            }
        }
        __syncthreads();

        // softmax over 16 slots (all lanes redundantly)
        float attn_me;
        {
            float mx = logit_s[srow0];
            for (int n = 1; n < 16; ++n) mx = fmaxf(mx, logit_s[srow0 + n]);
            float den = 0.0f;
            for (int n = 0; n < 16; ++n) den += expf(logit_s[srow0 + n] - mx);
            attn_me = expf(logit_s[srow0 + l15] - mx) / den;
        }

        // ---- GRU via MFMA ----
        {
            FragU auh[4], aul[4], ash[4], asl[4];
#pragma unroll
            for (int ks = 0; ks < 4; ++ks) {
                mk_scaled(v_s + g * 132 + ks * 32 + quad * 8, attn_me, auh[ks], aul[ks]);
                mk_raw(slots_s + (srow0 + l15) * 132 + ks * 32 + quad * 8, ash[ks], asl[ks]);
            }
            for (int cg = 0; cg < 8; ++cg) {
                f32x4 ar = {0}, az = {0}, ani = {0}, anh = {0};
                const int rowb = cg * 16 + l15;
#pragma unroll
                for (int ks = 0; ks < 4; ++ks) {
                    const int koff = ks * 32 + quad * 8;
                    FragU b;
                    b.u = *(const uint4*)(ws + OFF_WIHT + rowb * 128 + koff);
                    MFMA2(ar, auh[ks].v, aul[ks].v, b.v);
                    b.u = *(const uint4*)(ws + OFF_WHHT + rowb * 128 + koff);
                    MFMA2(ar, ash[ks].v, asl[ks].v, b.v);
                    b.u = *(const uint4*)(ws + OFF_WIHT + (128 + rowb) * 128 + koff);
                    MFMA2(az, auh[ks].v, aul[ks].v, b.v);
                    b.u = *(const uint4*)(ws + OFF_WHHT + (128 + rowb) * 128 + koff);
                    MFMA2(az, ash[ks].v, asl[ks].v, b.v);
                    b.u = *(const uint4*)(ws + OFF_WIHT + (256 + rowb) * 128 + koff);
                    MFMA2(ani, auh[ks].v, aul[ks].v, b.v);
                    b.u = *(const uint4*)(ws + OFF_WHHT + (256 + rowb) * 128 + koff);
                    MFMA2(anh, ash[ks].v, asl[ks].v, b.v);
                }
                const int cc = cg * 16 + l15;
#pragma unroll
                for (int reg = 0; reg < 4; ++reg) {
                    int row = srow0 + quad * 4 + reg;
                    float rg = sigmoidf_(ar[reg] + bias_s[cc]);
                    float zg = sigmoidf_(az[reg] + bias_s[128 + cc]);
                    float ng = tanhf(ani[reg] + bias_s[256 + cc] + rg * (anh[reg] + bias_s[384 + cc]));
                    float hp = slots_s[row * 132 + cc];
                    slots_s[row * 132 + cc] = (1.0f - zg) * ng + zg * hp;
                }
            }
        }
        __syncthreads();

        // ---- MLP: slots += relu(LN(slots)@W1+b1)@W2+b2 ----
        {
            const float* rowp = slots_s + (srow0 + l15) * 132;
            float s = 0.0f;
            for (int j = 0; j < 32; ++j) s += rowp[quad + 4 * j];
            s += __shfl_xor(s, 16); s += __shfl_xor(s, 32);
            float mu2 = s * (1.0f / 128.0f);
            float v = 0.0f;
            for (int j = 0; j < 32; ++j) { float d = rowp[quad + 4 * j] - mu2; v = fmaf(d, d, v); }
            v += __shfl_xor(v, 16); v += __shfl_xor(v, 32);
            float rs2 = rsqrtf(v * (1.0f / 128.0f) + 1e-5f);

            FragU ah[4], al[4];
#pragma unroll
            for (int ks = 0; ks < 4; ++ks)
                mk_aff(rowp + ks * 32 + quad * 8, mu2, rs2,
                       par_s + 512 + ks * 32 + quad * 8, par_s + 640 + ks * 32 + quad * 8,
                       ah[ks], al[ks]);
            for (int t = 0; t < 8; ++t) {
                f32x4 a = {0};
#pragma unroll
                for (int ks = 0; ks < 4; ++ks) {
                    FragU b; b.u = *(const uint4*)(ws + OFF_MW1T + (t * 16 + l15) * 128 + ks * 32 + quad * 8);
                    MFMA2(a, ah[ks].v, al[ks].v, b.v);
                }
                int cc = t * 16 + l15;
                float bb = mb1[cc];
#pragma unroll
                for (int reg = 0; reg < 4; ++reg)
                    hid_s[(srow0 + quad * 4 + reg) * 136 + cc] = f2b(fmaxf(a[reg] + bb, 0.0f));
            }
        }
        __syncthreads();
        {
            FragU hf[4];
#pragma unroll
            for (int ks = 0; ks < 4; ++ks)
                hf[ks].u = *(const uint4*)(hid_s + (srow0 + l15) * 136 + ks * 32 + quad * 8);
            for (int t = 0; t < 8; ++t) {
                f32x4 a = {0};
#pragma unroll
                for (int ks = 0; ks < 4; ++ks) {
                    FragU b; b.u = *(const uint4*)(ws + OFF_MW2T + (t * 16 + l15) * 128 + ks * 32 + quad * 8);
                    MFMA(a, hf[ks].v, b.v);
                }
                int cc = t * 16 + l15;
                float bb = mb2[cc];
#pragma unroll
                for (int reg = 0; reg < 4; ++reg)
                    slots_s[(srow0 + quad * 4 + reg) * 132 + cc] += a[reg] + bb;
            }
        }
        __syncthreads();
    }

    // ---- F.normalize + store ----
    {
        const float* rowp = slots_s + (srow0 + l15) * 132;
        float ss = 0.0f;
        for (int j = 0; j < 32; ++j) { float x = rowp[quad + 4 * j]; ss = fmaf(x, x, ss); }
        ss += __shfl_xor(ss, 16); ss += __shfl_xor(ss, 32);
        if (quad == 0) rs_s[srow0 + l15] = 1.0f / fmaxf(sqrtf(ss), 1e-8f);
    }
    __syncthreads();
    {
        size_t base = (size_t)(r0 + g) * 2048;
        for (int i = lane; i < 2048; i += 64) {
            int row = i >> 7;
            out[base + i] = slots_s[(srow0 + row) * 132 + (i & 127)] * rs_s[srow0 + row];
        }
    }
}

// ---------------- temporal chain: one block per batch row, 63 steps ----------------
__global__ __launch_bounds__(64) void temporal2_kernel(
    const u16* __restrict__ ws, float* __restrict__ out)
{
    __shared__ __align__(16) u16 wt_s[128 * 136];
    __shared__ __align__(16) u16 prev_s[16 * 136];
    __shared__ __align__(16) float sa_s[16 * 132];

    const int lane = threadIdx.x;
    const int l15 = lane & 15, quad = lane >> 4;
    const int b = blockIdx.x;

    for (int idx = lane; idx < 2048; idx += 64) {
        int row = idx >> 4, ch = idx & 15;
        *(uint4*)(wt_s + row * 136 + ch * 8) = *(const uint4*)(ws + OFF_WTT + row * 128 + ch * 8);
    }
    {
        size_t base0 = (size_t)b * 64 * 2048;
        for (int i = lane; i < 2048; i += 64)
            prev_s[(i >> 7) * 136 + (i & 127)] = f2b(out[base0 + i]);
    }
    __syncthreads();

    for (int t = 1; t < 64; ++t) {
        size_t base = ((size_t)b * 64 + t) * 2048;
        __syncthreads();  // prev_s from previous step visible
        FragU ap[4];
#pragma unroll
        for (int ks = 0; ks < 4; ++ks)
            ap[ks].u = *(const uint4*)(prev_s + l15 * 136 + ks * 32 + quad * 8);
        for (int i = lane; i < 2048; i += 64)
            sa_s[(i >> 7) * 132 + (i & 127)] = out[base + i];
        f32x4 acc[8] = {{0}, {0}, {0}, {0}, {0}, {0}, {0}, {0}};
#pragma unroll
        for (int tt = 0; tt < 8; ++tt) {
#pragma unroll
            for (int ks = 0; ks < 4; ++ks) {
                FragU bv; bv.u = *(const uint4*)(wt_s + (tt * 16 + l15) * 136 + ks * 32 + quad * 8);
                MFMA(acc[tt], ap[ks].v, bv.v);
            }
        }
        __syncthreads();  // sa_s ready
#pragma unroll
        for (int tt = 0; tt < 8; ++tt) {
            int col = tt * 16 + l15;
#pragma unroll
            for (int reg = 0; reg < 4; ++reg) {
                int row = quad * 4 + reg;
                float bl = 0.7f * sa_s[row * 132 + col] + 0.3f * tanhf(acc[tt][reg]);
                out[base + row * 128 + col] = bl;
                prev_s[row * 136 + col] = f2b(bl);
            }
        }
    }
}

extern "C" void kernel_launch(void* const* d_in, const int* in_sizes, int n_in,
                              void* d_out, int out_size, void* d_ws, size_t ws_size,
                              hipStream_t stream) {
    const float* obs   = (const float*)d_in[0];
    const float* eW1   = (const float*)d_in[1];
    const float* eb1   = (const float*)d_in[2];
    const float* eW2   = (const float*)d_in[3];
    const float* eb2   = (const float*)d_in[4];
    const float* skipW = (const float*)d_in[5];
    const float* smu   = (const float*)d_in[6];
    const float* Wk    = (const float*)d_in[7];
    const float* Wv    = (const float*)d_in[8];
    const float* Wq    = (const float*)d_in[9];
    const float* Wih   = (const float*)d_in[10];
    const float* Whh   = (const float*)d_in[11];
    const float* bih   = (const float*)d_in[12];
    const float* bhh   = (const float*)d_in[13];
    const float* mW1   = (const float*)d_in[14];
    const float* mb1   = (const float*)d_in[15];
    const float* mW2   = (const float*)d_in[16];
    const float* mb2   = (const float*)d_in[17];
    const float* g_in  = (const float*)d_in[18];
    const float* be_in = (const float*)d_in[19];
    const float* g_sl  = (const float*)d_in[20];
    const float* be_sl = (const float*)d_in[21];
    const float* g_ml  = (const float*)d_in[22];
    const float* be_ml = (const float*)d_in[23];
    const float* Wt    = (const float*)d_in[24];
    float* out = (float*)d_out;
    u16* ws = (u16*)d_ws;

    prep_kernel<<<dim3(512, 11), 256, 0, stream>>>(eW1, eW2, skipW, Wk, Wv, Wq,
                                                   Wih, Whh, mW1, mW2, Wt, ws);
    sa2_kernel<<<B_ * T_ / 4, 256, 0, stream>>>(obs, eb1, eb2, smu, bih, bhh, mb1, mb2,
                                                g_in, be_in, g_sl, be_sl, g_ml, be_ml,
                                                ws, out);
    temporal2_kernel<<<B_, 64, 0, stream>>>(ws, out);
}